// Round 3
// baseline (1842.624 us; speedup 1.0000x reference)
//
#include <hip/hip_runtime.h>

// Problem dims (fixed by the reference)
#define BB 4        // batch
#define CC 4096     // channels
#define TT 2048     // timesteps
#define BS 16       // block size
#define KK 100      // IRF taps
#define NNZ 1024    // nonzero blocks
#define NB (CC / BS)
#define TC 256              // timestep chunk per WG
#define NCH (TT / TC)       // 8 chunks
#define MAXM 64             // max blocks per output row

// acc + DPP-permuted src (GCNDPPCombine fuses mov_dpp+add -> v_add_f32_dpp)
template <int CTRL>
__device__ __forceinline__ float add_dpp(float acc, float src) {
    int m = __builtin_amdgcn_update_dpp(0, __builtin_bit_cast(int, src),
                                        CTRL, 0xF, 0xF, true);
    return acc + __builtin_bit_cast(float, m);
}
// acc + (src from lane^4) via ds_swizzle (LDS pipe, otherwise idle)
__device__ __forceinline__ float add_xor4(float acc, float src) {
    int m = __builtin_amdgcn_ds_swizzle(__builtin_bit_cast(int, src), 0x101F);
    return acc + __builtin_bit_cast(float, m);
}

// ------------- prep: per-row block lists, deterministic (no atomics) -------
__global__ void lti_build_lists(const int* __restrict__ rows,
                                int* __restrict__ cnt,
                                int* __restrict__ list) {
    int r = threadIdx.x;            // one thread per output row, single WG
    if (r >= NB) return;
    int m = 0;
    for (int n = 0; n < NNZ; ++n)
        if (rows[n] == r && m < MAXM) list[r * MAXM + m++] = n;
    cnt[r] = m;
}

// ------------- router: one WG per (row-block r, batch b, t-chunk) ----------
// Pure-IIR recursion (a^100 ~ e^-5 truncation error, far under threshold).
// No LDS staging, no syncthreads: waves are independent (16 j-lanes x 4 i).
__global__ __launch_bounds__(256) void lti_router(
    const float* __restrict__ x,       // runoff [B, C, T]
    const float* __restrict__ params,  // [NNZ, BS, BS]
    const int* __restrict__ cols,      // [NNZ]
    const int* __restrict__ cnt,       // [NB]
    const int* __restrict__ list,      // [NB, MAXM]
    float* __restrict__ out)           // [B, C, T]
{
    const int r   = blockIdx.x;
    const int b   = blockIdx.y;
    const int t0  = blockIdx.z * TC;
    const int tid = threadIdx.x;
    const int j   = tid & 15;          // input row within block
    const int i   = tid >> 4;          // output row within block

    const bool q0 = (j & 1) != 0;
    const bool q1 = (j & 2) != 0;
    const bool q2 = (j & 4) != 0;
    const bool q3 = (j & 8) != 0;

    // acc[p] accumulates y at t = t0 + p*16 + j (butterfly endpoint = lane j)
    float acc[16];
#pragma unroll
    for (int p = 0; p < 16; ++p) acc[p] = 0.0f;

    const int m = cnt[r];
    for (int bi = 0; bi < m; ++bi) {
        const int n = list[r * MAXM + bi];
        const int c = cols[n];
        const float pv  = params[n * (BS * BS) + tid];
        const float tau = 1.0f + 19.0f * pv;
        const float a   = __expf(-1.0f / tau);
        const float oma = 1.0f - a;

        const float* __restrict__ xr =
            x + ((size_t)b * CC + (size_t)c * BS + j) * TT;

        // bootstrap: s[t0-1] = sum_{k=0..99} a^k x[t0-1-k]  (Horner, f4 loads)
        float s = 0.0f;
        if (t0 != 0) {
            const float4* __restrict__ hp = (const float4*)(xr + t0 - KK);
#pragma unroll 5
            for (int k = 0; k < 25; ++k) {
                float4 h = hp[k];
                s = fmaf(a, s, h.x); s = fmaf(a, s, h.y);
                s = fmaf(a, s, h.z); s = fmaf(a, s, h.w);
            }
        }

        const float* __restrict__ xt = xr + t0;
        float4 A0 = *(const float4*)(xt + 0);
        float4 A1 = *(const float4*)(xt + 4);
        float4 A2 = *(const float4*)(xt + 8);
        float4 A3 = *(const float4*)(xt + 12);

#pragma unroll
        for (int tb = 0; tb < 16; ++tb) {
            float4 B0, B1, B2, B3;
            if (tb < 15) {               // prefetch next 16 timesteps
                const float* nx = xt + (tb + 1) * 16;
                B0 = *(const float4*)(nx + 0);
                B1 = *(const float4*)(nx + 4);
                B2 = *(const float4*)(nx + 8);
                B3 = *(const float4*)(nx + 12);
            }
            // 16 serial recursion steps: s = a*s + x[t]; v = (1-a)*s
            float v[16];
            s = fmaf(a, s, A0.x); v[0]  = oma * s;
            s = fmaf(a, s, A0.y); v[1]  = oma * s;
            s = fmaf(a, s, A0.z); v[2]  = oma * s;
            s = fmaf(a, s, A0.w); v[3]  = oma * s;
            s = fmaf(a, s, A1.x); v[4]  = oma * s;
            s = fmaf(a, s, A1.y); v[5]  = oma * s;
            s = fmaf(a, s, A1.z); v[6]  = oma * s;
            s = fmaf(a, s, A1.w); v[7]  = oma * s;
            s = fmaf(a, s, A2.x); v[8]  = oma * s;
            s = fmaf(a, s, A2.y); v[9]  = oma * s;
            s = fmaf(a, s, A2.z); v[10] = oma * s;
            s = fmaf(a, s, A2.w); v[11] = oma * s;
            s = fmaf(a, s, A3.x); v[12] = oma * s;
            s = fmaf(a, s, A3.y); v[13] = oma * s;
            s = fmaf(a, s, A3.z); v[14] = oma * s;
            s = fmaf(a, s, A3.w); v[15] = oma * s;

            // halving butterfly over j; lane j ends with sum for tau = j.
            // stage bit0: partner = j^1 (quad_perm [1,0,3,2])
            float u[8];
#pragma unroll
            for (int p2 = 0; p2 < 8; ++p2) {
                float keep = q0 ? v[2 * p2 + 1] : v[2 * p2];
                float send = q0 ? v[2 * p2]     : v[2 * p2 + 1];
                u[p2] = add_dpp<0xB1>(keep, send);
            }
            // stage bit1: partner = j^2 (quad_perm [2,3,0,1])
            float w[4];
#pragma unroll
            for (int p2 = 0; p2 < 4; ++p2) {
                float keep = q1 ? u[2 * p2 + 1] : u[2 * p2];
                float send = q1 ? u[2 * p2]     : u[2 * p2 + 1];
                w[p2] = add_dpp<0x4E>(keep, send);
            }
            // stage bit3: partner = j^8 (row_ror:8); pairs differ in bit3 -> (p2, p2+2)
            float z[2];
#pragma unroll
            for (int p2 = 0; p2 < 2; ++p2) {
                float keep = q3 ? w[p2 + 2] : w[p2];
                float send = q3 ? w[p2]     : w[p2 + 2];
                z[p2] = add_dpp<0x128>(keep, send);
            }
            // stage bit2: partner = j^4 (ds_swizzle)
            {
                float keep = q2 ? z[1] : z[0];
                float send = q2 ? z[0] : z[1];
                acc[tb] += add_xor4(keep, send);
            }
            A0 = B0; A1 = B1; A2 = B2; A3 = B3;
        }
    }

    // epilogue: out = runoff + y, each element written exactly once
    const size_t obase = ((size_t)b * CC + (size_t)r * BS + i) * TT + t0;
#pragma unroll
    for (int p = 0; p < 16; ++p) {
        const int t = p * 16 + j;
        out[obase + t] = x[obase + t] + acc[p];
    }
}

extern "C" void kernel_launch(void* const* d_in, const int* in_sizes, int n_in,
                              void* d_out, int out_size, void* d_ws, size_t ws_size,
                              hipStream_t stream) {
    const float* runoff = (const float*)d_in[0];
    const float* params = (const float*)d_in[1];
    const int* rows = (const int*)d_in[2];
    const int* cols = (const int*)d_in[3];
    float* out = (float*)d_out;

    // ws layout: cnt [NB] ints @ 0, list [NB*MAXM] ints @ 1024 bytes
    int* cnt  = (int*)d_ws;
    int* list = (int*)((char*)d_ws + 1024);

    lti_build_lists<<<1, 256, 0, stream>>>(rows, cnt, list);

    dim3 grid(NB, BB, NCH);
    lti_router<<<grid, 256, 0, stream>>>(runoff, params, cols, cnt, list, out);
}

// Round 4
// 561.022 us; speedup vs baseline: 3.2844x; 3.2844x over previous
//
#include <hip/hip_runtime.h>

// Problem dims (fixed by the reference)
#define BB 4        // batch
#define CC 4096     // channels
#define TT 2048     // timesteps
#define BS 16       // block size
#define KK 100      // IRF taps
#define NNZ 1024    // nonzero blocks
#define NB (CC / BS)
#define TC 256              // timestep chunk per WG
#define NCH (TT / TC)       // 8 chunks
#define MAXM 64             // max blocks per output row
#define WPAD 128            // history staged before t0 (>= KK, f4-aligned)
#define WIN (WPAD + TC)     // 384 staged floats per row
#define SSTR 388            // LDS row stride (mod 32 == 4, 16B-aligned)

// acc + DPP-permuted src (GCNDPPCombine fuses mov_dpp+add -> v_add_f32_dpp)
template <int CTRL>
__device__ __forceinline__ float add_dpp(float acc, float src) {
    int m = __builtin_amdgcn_update_dpp(0, __builtin_bit_cast(int, src),
                                        CTRL, 0xF, 0xF, true);
    return acc + __builtin_bit_cast(float, m);
}
// acc + (src from lane^4) via ds_swizzle
__device__ __forceinline__ float add_xor4(float acc, float src) {
    int m = __builtin_amdgcn_ds_swizzle(__builtin_bit_cast(int, src), 0x101F);
    return acc + __builtin_bit_cast(float, m);
}

// ------------- prep: per-row block lists, deterministic (no atomics) -------
__global__ void lti_build_lists(const int* __restrict__ rows,
                                int* __restrict__ cnt,
                                int* __restrict__ list) {
    int r = threadIdx.x;            // one thread per output row, single WG
    if (r >= NB) return;
    int m = 0;
    for (int n = 0; n < NNZ; ++n)
        if (rows[n] == r && m < MAXM) list[r * MAXM + m++] = n;
    cnt[r] = m;
}

// ------------- router: one WG per (row-block r, batch b, t-chunk) ----------
__global__ __launch_bounds__(256) void lti_router(
    const float* __restrict__ x,       // runoff [B, C, T]
    const float* __restrict__ params,  // [NNZ, BS, BS]
    const int* __restrict__ cols,      // [NNZ]
    const int* __restrict__ cnt,       // [NB]
    const int* __restrict__ list,      // [NB, MAXM]
    float* __restrict__ out)           // [B, C, T]
{
    const int r   = blockIdx.x;
    const int b   = blockIdx.y;
    const int t0  = blockIdx.z * TC;
    const int tid = threadIdx.x;
    const int j   = tid & 15;          // input row within block
    const int i   = tid >> 4;          // output row within block

    const bool q0 = (j & 1) != 0;
    const bool q1 = (j & 2) != 0;
    const bool q2 = (j & 4) != 0;
    const bool q3 = (j & 8) != 0;

    __shared__ __align__(16) float xs[16 * SSTR];

    // acc[p] accumulates y at t = t0 + p*16 + j (butterfly endpoint = lane j)
    float acc[16];
#pragma unroll
    for (int p = 0; p < 16; ++p) acc[p] = 0.0f;

    const int m = cnt[r];
    for (int bi = 0; bi < m; ++bi) {
        const int n = list[r * MAXM + bi];
        const int c = cols[n];

        // ---- stage x[b, c*16 + row, t0-128 .. t0+256) into LDS (f4) ----
        {
            const float* __restrict__ xb =
                x + ((size_t)b * CC + (size_t)c * BS) * TT;
#pragma unroll
            for (int k = 0; k < 6; ++k) {
                const int f    = tid + k * 256;      // 0 .. 1535
                const int row  = f / 96;             // 0 .. 15
                const int col4 = f - row * 96;       // 0 .. 95
                const int t    = t0 - WPAD + col4 * 4;
                float4 v;
                if (t >= 0) v = *(const float4*)(xb + (size_t)row * TT + t);
                else        v = make_float4(0.f, 0.f, 0.f, 0.f);
                *(float4*)&xs[row * SSTR + col4 * 4] = v;
            }
        }
        __syncthreads();

        // ---- per-entry IRF params ----
        const float pv  = params[n * (BS * BS) + tid];
        const float tau = 1.0f + 19.0f * pv;
        const float a   = __expf(-1.0f / tau);
        const float oma = 1.0f - a;

        const float* __restrict__ xj = &xs[j * SSTR];

        // ---- bootstrap: s[t0-1] = sum_{k=0..99} a^k x[t0-1-k] ----
        float s = 0.0f;
        if (t0 != 0) {
            // window idx of t0-100 is WPAD-100 = 28 (16B aligned)
#pragma unroll 5
            for (int q = 0; q < 25; ++q) {
                float4 h = *(const float4*)(xj + 28 + 4 * q);
                s = fmaf(a, s, h.x); s = fmaf(a, s, h.y);
                s = fmaf(a, s, h.z); s = fmaf(a, s, h.w);
            }
        }

        // ---- main recursion, 16 steps per tile, register double-buffer ----
        const float* __restrict__ xm = xj + WPAD;
        float4 A0 = *(const float4*)(xm + 0);
        float4 A1 = *(const float4*)(xm + 4);
        float4 A2 = *(const float4*)(xm + 8);
        float4 A3 = *(const float4*)(xm + 12);

#pragma unroll
        for (int tb = 0; tb < 16; ++tb) {
            float4 B0, B1, B2, B3;
            if (tb < 15) {
                const float* nx = xm + (tb + 1) * 16;
                B0 = *(const float4*)(nx + 0);
                B1 = *(const float4*)(nx + 4);
                B2 = *(const float4*)(nx + 8);
                B3 = *(const float4*)(nx + 12);
            }
            float v[16];
            s = fmaf(a, s, A0.x); v[0]  = oma * s;
            s = fmaf(a, s, A0.y); v[1]  = oma * s;
            s = fmaf(a, s, A0.z); v[2]  = oma * s;
            s = fmaf(a, s, A0.w); v[3]  = oma * s;
            s = fmaf(a, s, A1.x); v[4]  = oma * s;
            s = fmaf(a, s, A1.y); v[5]  = oma * s;
            s = fmaf(a, s, A1.z); v[6]  = oma * s;
            s = fmaf(a, s, A1.w); v[7]  = oma * s;
            s = fmaf(a, s, A2.x); v[8]  = oma * s;
            s = fmaf(a, s, A2.y); v[9]  = oma * s;
            s = fmaf(a, s, A2.z); v[10] = oma * s;
            s = fmaf(a, s, A2.w); v[11] = oma * s;
            s = fmaf(a, s, A3.x); v[12] = oma * s;
            s = fmaf(a, s, A3.y); v[13] = oma * s;
            s = fmaf(a, s, A3.z); v[14] = oma * s;
            s = fmaf(a, s, A3.w); v[15] = oma * s;

            // halving butterfly over j; lane j ends with the sum for t-phase j
            float u[8];
#pragma unroll
            for (int p2 = 0; p2 < 8; ++p2) {
                float keep = q0 ? v[2 * p2 + 1] : v[2 * p2];
                float send = q0 ? v[2 * p2]     : v[2 * p2 + 1];
                u[p2] = add_dpp<0xB1>(keep, send);     // xor 1
            }
            float w[4];
#pragma unroll
            for (int p2 = 0; p2 < 4; ++p2) {
                float keep = q1 ? u[2 * p2 + 1] : u[2 * p2];
                float send = q1 ? u[2 * p2]     : u[2 * p2 + 1];
                w[p2] = add_dpp<0x4E>(keep, send);     // xor 2
            }
            float z[2];
#pragma unroll
            for (int p2 = 0; p2 < 2; ++p2) {
                float keep = q3 ? w[p2 + 2] : w[p2];
                float send = q3 ? w[p2]     : w[p2 + 2];
                z[p2] = add_dpp<0x128>(keep, send);    // row_ror:8 (xor 8)
            }
            {
                float keep = q2 ? z[1] : z[0];
                float send = q2 ? z[0] : z[1];
                acc[tb] += add_xor4(keep, send);       // xor 4
            }
            A0 = B0; A1 = B1; A2 = B2; A3 = B3;
        }
        __syncthreads();   // before next block overwrites xs
    }

    // ---- epilogue: out = runoff + y, each element written exactly once ----
    const size_t obase = ((size_t)b * CC + (size_t)r * BS + i) * TT + t0;
#pragma unroll
    for (int p = 0; p < 16; ++p) {
        const int t = p * 16 + j;
        out[obase + t] = x[obase + t] + acc[p];
    }
}

extern "C" void kernel_launch(void* const* d_in, const int* in_sizes, int n_in,
                              void* d_out, int out_size, void* d_ws, size_t ws_size,
                              hipStream_t stream) {
    const float* runoff = (const float*)d_in[0];
    const float* params = (const float*)d_in[1];
    const int* rows = (const int*)d_in[2];
    const int* cols = (const int*)d_in[3];
    float* out = (float*)d_out;

    // ws layout: cnt [NB] ints @ 0, list [NB*MAXM] ints @ 1024 bytes
    int* cnt  = (int*)d_ws;
    int* list = (int*)((char*)d_ws + 1024);

    lti_build_lists<<<1, 256, 0, stream>>>(rows, cnt, list);

    dim3 grid(NB, BB, NCH);
    lti_router<<<grid, 256, 0, stream>>>(runoff, params, cols, cnt, list, out);
}